// Round 4
// baseline (416.596 us; speedup 1.0000x reference)
//
#include <hip/hip_runtime.h>
#include <hip/hip_bf16.h>

#define DDIM   256
#define KNBR   16
#define TWOD   512
#define ROWS_PB 16
#define NTHREADS 256

using bf16x8  = __attribute__((ext_vector_type(8))) short;
using short4v = __attribute__((ext_vector_type(4))) short;
using f32x4   = __attribute__((ext_vector_type(4))) float;

__device__ __forceinline__ short f2bf(float x) {
  unsigned int u;
  __builtin_memcpy(&u, &x, 4);
  u += 0x7FFFu + ((u >> 16) & 1u);   // RNE, inputs are never NaN
  return (short)(u >> 16);
}
__device__ __forceinline__ float bf2f(short s) {
  unsigned int u = ((unsigned int)(unsigned short)s) << 16;
  float f;
  __builtin_memcpy(&f, &u, 4);
  return f;
}

// Fallback B-fragment loader, direct from f32 row-major weight (mirror k-map g*8+i)
__device__ __forceinline__ bf16x8 ldWfrag(const float* __restrict__ W, int ld, int r, int c) {
  const float4* p = (const float4*)(W + (size_t)r * ld + c);
  float4 a = p[0];
  float4 b = p[1];
  bf16x8 o;
  o[0] = f2bf(a.x); o[1] = f2bf(a.y); o[2] = f2bf(a.z); o[3] = f2bf(a.w);
  o[4] = f2bf(b.x); o[5] = f2bf(b.y); o[6] = f2bf(b.z); o[7] = f2bf(b.w);
  return o;
}

// ---- prep: convert Wq/Wk/Wg f32 -> bf16 MFMA B-fragment arrays in ws ----
// layout (shorts): [0,16384) WqF (32 frags), [16384,32768) WkF (32), [32768,163840) WgF (256)
__global__ void prep_frags(const float* __restrict__ Wq,
                           const float* __restrict__ Wk,
                           const float* __restrict__ Wg,
                           short* __restrict__ F) {
  const int gid  = blockIdx.x * NTHREADS + threadIdx.x;
  const int lane = gid & 63;
  const int n16  = lane & 15;
  const int g4   = lane >> 4;
  const int f    = gid >> 6;                 // 0..319
  const float* src;
  short* dst;
  if (f < 32) {
    const int t = f >> 3, s = f & 7;
    src = Wq + (size_t)(t * 16 + n16) * DDIM + s * 32 + g4 * 8;
    dst = F + f * 512 + lane * 8;
  } else if (f < 64) {
    const int fq = f - 32;
    const int t = fq >> 3, s = fq & 7;
    src = Wk + (size_t)(t * 16 + n16) * DDIM + s * 32 + g4 * 8;
    dst = F + 16384 + fq * 512 + lane * 8;
  } else {
    const int fg = f - 64;                   // 0..255
    const int t4 = fg >> 4, s = fg & 15;
    src = Wg + (size_t)(t4 * 16 + n16) * TWOD + s * 32 + g4 * 8;
    dst = F + 32768 + fg * 512 + lane * 8;
  }
  float4 a = *(const float4*)src;
  float4 b = *(const float4*)(src + 4);
  bf16x8 o;
  o[0] = f2bf(a.x); o[1] = f2bf(a.y); o[2] = f2bf(a.z); o[3] = f2bf(a.w);
  o[4] = f2bf(b.x); o[5] = f2bf(b.y); o[6] = f2bf(b.z); o[7] = f2bf(b.w);
  *(bf16x8*)dst = o;
}

// Per-row body: RR is compile-time -> every index static -> no scratch.
template<bool FRAG, int RR>
__device__ __forceinline__ void row_body(
    int w, int lane, int n16, int g4, int row0,
    const float* __restrict__ neigh, const float* __restrict__ nwts,
    const short* __restrict__ WkF, const float* __restrict__ Wk,
    const f32x4 (&qacc)[4], const f32x4& bqv, const f32x4& bkv,
    short* __restrict__ sNbr, short* __restrict__ sCtx)
{
  const int rowl = w * 4 + RR;
  const size_t gr = (size_t)(row0 + rowl);
  const float4* np = (const float4*)(neigh + gr * (size_t)(KNBR * DDIM));

  // issue all 16 row loads up front (deep MLP), then convert+write
  float4 vb[8], vc[8];
  #pragma unroll
  for (int j = 0; j < 8; ++j) vb[j] = np[j * 64 + lane];
  #pragma unroll
  for (int j = 0; j < 8; ++j) vc[j] = np[(j + 8) * 64 + lane];
  #pragma unroll
  for (int j = 0; j < 8; ++j) {
    short4v o;
    o[0]=f2bf(vb[j].x); o[1]=f2bf(vb[j].y); o[2]=f2bf(vb[j].z); o[3]=f2bf(vb[j].w);
    *(short4v*)&sNbr[w * 4096 + ((j * 256 + lane * 4) ^ ((j & 7) << 3))] = o;
  }
  #pragma unroll
  for (int j = 0; j < 8; ++j) {
    short4v o;
    o[0]=f2bf(vc[j].x); o[1]=f2bf(vc[j].y); o[2]=f2bf(vc[j].z); o[3]=f2bf(vc[j].w);
    *(short4v*)&sNbr[w * 4096 + (((j + 8) * 256 + lane * 4) ^ (((j + 8) & 7) << 3))] = o;
  }

  // k-projection: M=16 neighbors, N=64, K=256
  f32x4 kacc[4];
  #pragma unroll
  for (int t = 0; t < 4; ++t) { kacc[t][0]=0.f; kacc[t][1]=0.f; kacc[t][2]=0.f; kacc[t][3]=0.f; }
  #pragma unroll
  for (int s = 0; s < 8; ++s) {
    bf16x8 af = *(const bf16x8*)&sNbr[w * 4096 +
                  ((n16 * 256 + s * 32 + g4 * 8) ^ ((n16 & 7) << 3))];
    #pragma unroll
    for (int t = 0; t < 4; ++t) {
      bf16x8 bfr = FRAG ? *(const bf16x8*)&WkF[(t * 8 + s) * 512 + lane * 8]
                        : ldWfrag(Wk, DDIM, t * 16 + n16, s * 32 + g4 * 8);
      kacc[t] = __builtin_amdgcn_mfma_f32_16x16x32_bf16(af, bfr, kacc[t], 0, 0, 0);
    }
  }

  // logits partials: lane holds k[j=g4*4+r][a=16t+n16] (+bias); dot with q
  f32x4 part;
  part[0]=0.f; part[1]=0.f; part[2]=0.f; part[3]=0.f;
  #pragma unroll
  for (int t = 0; t < 4; ++t) {
    const float qv = __shfl(qacc[t][RR] + bqv[t], w * 16 + n16);
    #pragma unroll
    for (int r = 0; r < 4; ++r) part[r] += qv * (kacc[t][r] + bkv[t]);
  }
  #pragma unroll
  for (int off = 1; off < 16; off <<= 1) {
    #pragma unroll
    for (int r = 0; r < 4; ++r) part[r] += __shfl_xor(part[r], off);
  }
  // broadcast logits to all lanes, softmax (all static indices)
  f32x4 lg[4];
  #pragma unroll
  for (int j = 0; j < 16; ++j)
    lg[j >> 2][j & 3] = 0.125f * __shfl(part[j & 3], (j >> 2) << 4);
  float mx = -1e30f;
  #pragma unroll
  for (int j = 0; j < 16; ++j) mx = fmaxf(mx, lg[j >> 2][j & 3]);
  float sum = 0.f;
  #pragma unroll
  for (int j = 0; j < 16; ++j) {
    const float e = __expf(lg[j >> 2][j & 3] - mx);
    lg[j >> 2][j & 3] = e; sum += e;
  }
  const float rs = 1.f / sum;
  float den = 1e-8f;
  #pragma unroll
  for (int q4 = 0; q4 < 4; ++q4) {
    f32x4 wvq = *(const f32x4*)(nwts + gr * KNBR + q4 * 4);   // lazy, transient
    #pragma unroll
    for (int e = 0; e < 4; ++e) {
      const float a = lg[q4][e] * rs * wvq[e];
      lg[q4][e] = a; den += a;
    }
  }
  const float rd = 1.f / den;

  // context: lane owns dims lane*4..+3
  f32x4 cx;
  cx[0]=0.f; cx[1]=0.f; cx[2]=0.f; cx[3]=0.f;
  #pragma unroll
  for (int j = 0; j < 16; ++j) {
    short4v nv = *(const short4v*)&sNbr[w * 4096 +
                   ((j * 256 + lane * 4) ^ ((j & 7) << 3))];
    const float aj = lg[j >> 2][j & 3];
    cx[0] += aj * bf2f(nv[0]);
    cx[1] += aj * bf2f(nv[1]);
    cx[2] += aj * bf2f(nv[2]);
    cx[3] += aj * bf2f(nv[3]);
  }
  short4v co;
  co[0] = f2bf(cx[0] * rd); co[1] = f2bf(cx[1] * rd);
  co[2] = f2bf(cx[2] * rd); co[3] = f2bf(cx[3] * rd);
  *(short4v*)&sCtx[(rowl * 256 + lane * 4) ^ ((rowl & 7) << 3)] = co;
}

// LDS: sNbr 32KB (4 waves x [16][256] bf16, swizzled), sCen 8KB, sCtx 8KB
template<bool FRAG>
__global__ __launch_bounds__(NTHREADS, 3)
void natt_fused(const float* __restrict__ center,
                const float* __restrict__ neigh,
                const float* __restrict__ nwts,
                const void*  __restrict__ vmask,
                const short* __restrict__ WF,
                const float* __restrict__ Wq, const float* __restrict__ bq,
                const float* __restrict__ Wk, const float* __restrict__ bk,
                const float* __restrict__ Wg, const float* __restrict__ bg,
                float* __restrict__ out)
{
  __shared__ __align__(16) short sNbr[16384];
  __shared__ __align__(16) short sCen[4096];
  __shared__ __align__(16) short sCtx[4096];
  const int tid  = threadIdx.x;
  const int lane = tid & 63;
  const int w    = tid >> 6;
  const int n16  = lane & 15;
  const int g4   = lane >> 4;
  const int row0 = blockIdx.x * ROWS_PB;
  const unsigned char* mb = (const unsigned char*)vmask;
  const short* WqF = WF;
  const short* WkF = WF + 16384;
  const short* WgF = WF + 32768;

  // ---- valid_mask dtype detection (1-byte bool vs 4-byte), wave-uniform ----
  const unsigned char x1 = mb[lane * 4 + 1];
  const unsigned char x2 = mb[lane * 4 + 2];
  const unsigned char x3 = mb[lane * 4 + 3];
  const bool anyGe2 = __ballot((x1 >= 2) || (x2 >= 2) || (x3 >= 2)) != 0ULL;
  const bool anyNz  = __ballot(((x1 | x2) | x3) != 0) != 0ULL;
  const bool maskIsByte = anyNz && !anyGe2;

  // ---- stage center tile -> sCen bf16 (coalesced, swizzled) ----
  #pragma unroll
  for (int it = 0; it < 4; ++it) {
    const int row = it * 4 + w;
    const int d   = lane * 4;
    float4 v = *(const float4*)(center + (size_t)(row0 + row) * DDIM + d);
    short4v o;
    o[0] = f2bf(v.x); o[1] = f2bf(v.y); o[2] = f2bf(v.z); o[3] = f2bf(v.w);
    *(short4v*)&sCen[(row * 256 + d) ^ ((row & 7) << 3)] = o;
  }
  __syncthreads();

  // ---- q-projection (each wave computes q[16][64] redundantly) ----
  f32x4 qacc[4];
  #pragma unroll
  for (int t = 0; t < 4; ++t) { qacc[t][0]=0.f; qacc[t][1]=0.f; qacc[t][2]=0.f; qacc[t][3]=0.f; }
  #pragma unroll
  for (int s = 0; s < 8; ++s) {
    bf16x8 af = *(const bf16x8*)&sCen[(n16 * 256 + s * 32 + g4 * 8) ^ ((n16 & 7) << 3)];
    #pragma unroll
    for (int t = 0; t < 4; ++t) {
      bf16x8 bfr = FRAG ? *(const bf16x8*)&WqF[(t * 8 + s) * 512 + lane * 8]
                        : ldWfrag(Wq, DDIM, t * 16 + n16, s * 32 + g4 * 8);
      qacc[t] = __builtin_amdgcn_mfma_f32_16x16x32_bf16(af, bfr, qacc[t], 0, 0, 0);
    }
  }
  f32x4 bqv, bkv;
  #pragma unroll
  for (int t = 0; t < 4; ++t) { bqv[t] = bq[t * 16 + n16]; bkv[t] = bk[t * 16 + n16]; }

  // ---- 4 rows per wave, compile-time RR (no runtime-indexed state) ----
  row_body<FRAG, 0>(w, lane, n16, g4, row0, neigh, nwts, WkF, Wk, qacc, bqv, bkv, sNbr, sCtx);
  row_body<FRAG, 1>(w, lane, n16, g4, row0, neigh, nwts, WkF, Wk, qacc, bqv, bkv, sNbr, sCtx);
  row_body<FRAG, 2>(w, lane, n16, g4, row0, neigh, nwts, WkF, Wk, qacc, bqv, bkv, sNbr, sCtx);
  row_body<FRAG, 3>(w, lane, n16, g4, row0, neigh, nwts, WkF, Wk, qacc, bqv, bkv, sNbr, sCtx);
  __syncthreads();

  // ---- gate GEMM (M=16 rows, N=256, K=512) + fused epilogue ----
  f32x4 gacc[4];
  #pragma unroll
  for (int t = 0; t < 4; ++t) { gacc[t][0]=0.f; gacc[t][1]=0.f; gacc[t][2]=0.f; gacc[t][3]=0.f; }
  #pragma unroll
  for (int s = 0; s < 16; ++s) {
    bf16x8 af;
    if (s < 8) {
      af = *(const bf16x8*)&sCen[(n16 * 256 + s * 32 + g4 * 8) ^ ((n16 & 7) << 3)];
    } else {
      af = *(const bf16x8*)&sCtx[(n16 * 256 + (s - 8) * 32 + g4 * 8) ^ ((n16 & 7) << 3)];
    }
    #pragma unroll
    for (int tt = 0; tt < 4; ++tt) {
      bf16x8 bfr = FRAG ? *(const bf16x8*)&WgF[(((w * 4 + tt) * 16) + s) * 512 + lane * 8]
                        : ldWfrag(Wg, TWOD, (w * 4 + tt) * 16 + n16, s * 32 + g4 * 8);
      gacc[tt] = __builtin_amdgcn_mfma_f32_16x16x32_bf16(af, bfr, gacc[tt], 0, 0, 0);
    }
  }
  #pragma unroll
  for (int tt = 0; tt < 4; ++tt) {
    const int dout = (w * 4 + tt) * 16 + n16;
    const float bga = bg[dout];
    #pragma unroll
    for (int r = 0; r < 4; ++r) {
      const int rowl = g4 * 4 + r;
      const size_t gr = (size_t)(row0 + rowl);
      const float pre  = gacc[tt][r] + bga;
      const float gate = 1.f / (1.f + __expf(-pre));
      const float cen  = center[gr * DDIM + dout];
      const float cxv  = bf2f(sCtx[(rowl * 256 + dout) ^ ((rowl & 7) << 3)]);
      const float fused = gate * cen + (1.f - gate) * cxv;
      const bool valid = maskIsByte ? (mb[gr] != 0)
                                    : (((const unsigned int*)vmask)[gr] != 0u);
      out[gr * DDIM + dout] = valid ? fused : cen;
    }
  }
}

extern "C" void kernel_launch(void* const* d_in, const int* in_sizes, int n_in,
                              void* d_out, int out_size, void* d_ws, size_t ws_size,
                              hipStream_t stream) {
  const float* center = (const float*)d_in[0];
  const float* neigh  = (const float*)d_in[1];
  const float* nwts   = (const float*)d_in[2];
  const void*  vm     = d_in[3];
  const float* Wq = (const float*)d_in[4];
  const float* bq = (const float*)d_in[5];
  const float* Wk = (const float*)d_in[6];
  const float* bk = (const float*)d_in[7];
  const float* Wg = (const float*)d_in[8];
  const float* bg = (const float*)d_in[9];
  float* out = (float*)d_out;
  short* WF = (short*)d_ws;

  const int nrows = in_sizes[0] / DDIM;           // 32768
  dim3 grid(nrows / ROWS_PB), block(NTHREADS);

  const bool frag = ws_size >= (size_t)163840 * sizeof(short);
  if (frag) {
    hipLaunchKernelGGL(prep_frags, dim3(80), dim3(NTHREADS), 0, stream, Wq, Wk, Wg, WF);
    hipLaunchKernelGGL((natt_fused<true>), grid, block, 0, stream,
                       center, neigh, nwts, vm, WF, Wq, bq, Wk, bk, Wg, bg, out);
  } else {
    hipLaunchKernelGGL((natt_fused<false>), grid, block, 0, stream,
                       center, neigh, nwts, vm, WF, Wq, bq, Wk, bk, Wg, bg, out);
  }
}

// Round 8
// 263.639 us; speedup vs baseline: 1.5802x; 1.5802x over previous
//
#include <hip/hip_runtime.h>
#include <hip/hip_bf16.h>

#define DDIM   256
#define KNBR   16
#define TWOD   512
#define NTHREADS 256

using bf16x8  = __attribute__((ext_vector_type(8))) short;
using short4v = __attribute__((ext_vector_type(4))) short;
using f32x4   = __attribute__((ext_vector_type(4))) float;

// ---- ws layout (shorts): WqF [0,16384) | WkF [16384,32768) | WgF [32768,163840)
//      ctxg bf16 [32768][256] at short offset 163840 (16MB)
#define CTX_SOFF 163840u
#define WS_NEED  (327680u + 16777216u)

__device__ __forceinline__ short f2bf(float x) {
  unsigned int u;
  __builtin_memcpy(&u, &x, 4);
  u += 0x7FFFu + ((u >> 16) & 1u);   // RNE
  return (short)(u >> 16);
}
__device__ __forceinline__ float bf2f(short s) {
  unsigned int u = ((unsigned int)(unsigned short)s) << 16;
  float f;
  __builtin_memcpy(&f, &u, 4);
  return f;
}

// Verified B-fragment loader, direct from f32 row-major weight (mirror k-map g4*8+i)
__device__ __forceinline__ bf16x8 ldWfrag(const float* __restrict__ W, int ld, int r, int c) {
  const float4* p = (const float4*)(W + (size_t)r * ld + c);
  float4 a = p[0];
  float4 b = p[1];
  bf16x8 o;
  o[0] = f2bf(a.x); o[1] = f2bf(a.y); o[2] = f2bf(a.z); o[3] = f2bf(a.w);
  o[4] = f2bf(b.x); o[5] = f2bf(b.y); o[6] = f2bf(b.z); o[7] = f2bf(b.w);
  return o;
}

// ---- prep_frags: VERBATIM r2/r3 (HW-passed). WqF(32) WkF(32) WgF(256) ----
__global__ void prep_frags(const float* __restrict__ Wq,
                           const float* __restrict__ Wk,
                           const float* __restrict__ Wg,
                           short* __restrict__ F) {
  const int gid  = blockIdx.x * NTHREADS + threadIdx.x;
  const int lane = gid & 63;
  const int n16  = lane & 15;
  const int g4   = lane >> 4;
  const int f    = gid >> 6;                 // 0..319
  const float* src;
  short* dst;
  if (f < 32) {
    const int t = f >> 3, s = f & 7;
    src = Wq + (size_t)(t * 16 + n16) * DDIM + s * 32 + g4 * 8;
    dst = F + f * 512 + lane * 8;
  } else if (f < 64) {
    const int fq = f - 32;
    const int t = fq >> 3, s = fq & 7;
    src = Wk + (size_t)(t * 16 + n16) * DDIM + s * 32 + g4 * 8;
    dst = F + 16384 + fq * 512 + lane * 8;
  } else {
    const int fg = f - 64;                   // 0..255
    const int t4 = fg >> 4, s = fg & 15;
    src = Wg + (size_t)(t4 * 16 + n16) * TWOD + s * 32 + g4 * 8;
    dst = F + 32768 + fg * 512 + lane * 8;
  }
  float4 a = *(const float4*)src;
  float4 b = *(const float4*)(src + 4);
  bf16x8 o;
  o[0] = f2bf(a.x); o[1] = f2bf(a.y); o[2] = f2bf(a.z); o[3] = f2bf(a.w);
  o[4] = f2bf(b.x); o[5] = f2bf(b.y); o[6] = f2bf(b.z); o[7] = f2bf(b.w);
  *(bf16x8*)dst = o;
}

// ==================== Kernel A: attention/context, 4 rows/block, 1 row/wave ====================
// LDS: sNbr 32KB (4 waves x [16][256] bf16 swz), sCen 2KB ([4][256] bf16 swz)
__global__ __launch_bounds__(NTHREADS, 4)
void natt_ctx(const float* __restrict__ center, const float* __restrict__ neigh,
              const float* __restrict__ nwts,
              const short* __restrict__ WF,
              const float* __restrict__ bq, const float* __restrict__ bk,
              short* __restrict__ ctxg) {
  __shared__ __align__(16) short sNbr[16384];
  __shared__ __align__(16) short sCen[1024];
  const int tid  = threadIdx.x;
  const int lane = tid & 63;
  const int w    = tid >> 6;
  const int n16  = lane & 15;
  const int g4   = lane >> 4;
  const int row0 = blockIdx.x * 4;
  const short* WqF = WF;
  const short* WkF = WF + 16384;

  // ---- stage 4 center rows (wave w stages row w) ----
  {
    float4 v = *(const float4*)(center + (size_t)(row0 + w) * DDIM + lane * 4);
    short4v o;
    o[0] = f2bf(v.x); o[1] = f2bf(v.y); o[2] = f2bf(v.z); o[3] = f2bf(v.w);
    *(short4v*)&sCen[(w * 256 + lane * 4) ^ (w << 3)] = o;
  }
  __syncthreads();

  // ---- q-projection (each wave redundant; A rows replicated n16&3) ----
  f32x4 qacc[4];
  #pragma unroll
  for (int t = 0; t < 4; ++t) { qacc[t][0]=0.f; qacc[t][1]=0.f; qacc[t][2]=0.f; qacc[t][3]=0.f; }
  #pragma unroll
  for (int s = 0; s < 8; ++s) {
    const int cr = n16 & 3;
    bf16x8 af = *(const bf16x8*)&sCen[(cr * 256 + s * 32 + g4 * 8) ^ (cr << 3)];
    #pragma unroll
    for (int t = 0; t < 4; ++t) {
      bf16x8 bfr = *(const bf16x8*)&WqF[(t * 8 + s) * 512 + lane * 8];
      qacc[t] = __builtin_amdgcn_mfma_f32_16x16x32_bf16(af, bfr, qacc[t], 0, 0, 0);
    }
  }
  // wave w needs q[w][16t+n16]: row w is reg r=w at lanes g4=0 (out row = 0*4+w, A row w&3=w)
  f32x4 qvv, bkv;
  #pragma unroll
  for (int t = 0; t < 4; ++t) {
    const float bqa = bq[t * 16 + n16];
    const float s0 = qacc[t][0] + bqa;
    const float s1 = qacc[t][1] + bqa;
    const float s2 = qacc[t][2] + bqa;
    const float s3 = qacc[t][3] + bqa;
    const float sel = (w == 0) ? s0 : ((w == 1) ? s1 : ((w == 2) ? s2 : s3)); // wave-uniform
    qvv[t] = __shfl(sel, n16);
    bkv[t] = bk[t * 16 + n16];
  }

  // ---- single row per wave ----
  const size_t gr = (size_t)(row0 + w);
  const float4* np = (const float4*)(neigh + gr * (size_t)(KNBR * DDIM));

  // stage neighbors in two 8-batches (verified r3 pattern)
  {
    float4 vb[8];
    #pragma unroll
    for (int j = 0; j < 8; ++j) vb[j] = np[j * 64 + lane];
    #pragma unroll
    for (int j = 0; j < 8; ++j) {
      short4v o;
      o[0]=f2bf(vb[j].x); o[1]=f2bf(vb[j].y); o[2]=f2bf(vb[j].z); o[3]=f2bf(vb[j].w);
      *(short4v*)&sNbr[w * 4096 + ((j * 256 + lane * 4) ^ ((j & 7) << 3))] = o;
    }
    #pragma unroll
    for (int j = 0; j < 8; ++j) vb[j] = np[(j + 8) * 64 + lane];
    #pragma unroll
    for (int j = 0; j < 8; ++j) {
      short4v o;
      o[0]=f2bf(vb[j].x); o[1]=f2bf(vb[j].y); o[2]=f2bf(vb[j].z); o[3]=f2bf(vb[j].w);
      *(short4v*)&sNbr[w * 4096 + (((j + 8) * 256 + lane * 4) ^ (((j + 8) & 7) << 3))] = o;
    }
  }

  // k-projection: M=16 neighbors, N=64, K=256 (verified)
  f32x4 kacc[4];
  #pragma unroll
  for (int t = 0; t < 4; ++t) { kacc[t][0]=0.f; kacc[t][1]=0.f; kacc[t][2]=0.f; kacc[t][3]=0.f; }
  #pragma unroll
  for (int s = 0; s < 8; ++s) {
    bf16x8 af = *(const bf16x8*)&sNbr[w * 4096 +
                  ((n16 * 256 + s * 32 + g4 * 8) ^ ((n16 & 7) << 3))];
    #pragma unroll
    for (int t = 0; t < 4; ++t) {
      bf16x8 bfr = *(const bf16x8*)&WkF[(t * 8 + s) * 512 + lane * 8];
      kacc[t] = __builtin_amdgcn_mfma_f32_16x16x32_bf16(af, bfr, kacc[t], 0, 0, 0);
    }
  }

  // logits: lane holds k[j=g4*4+r][a=16t+n16] (+bias); dot with q (verified)
  f32x4 part;
  part[0]=0.f; part[1]=0.f; part[2]=0.f; part[3]=0.f;
  #pragma unroll
  for (int t = 0; t < 4; ++t) {
    #pragma unroll
    for (int r = 0; r < 4; ++r) part[r] += qvv[t] * (kacc[t][r] + bkv[t]);
  }
  #pragma unroll
  for (int off = 1; off < 16; off <<= 1) {
    #pragma unroll
    for (int r = 0; r < 4; ++r) part[r] += __shfl_xor(part[r], off);
  }
  f32x4 lg[4];
  #pragma unroll
  for (int j = 0; j < 16; ++j)
    lg[j >> 2][j & 3] = 0.125f * __shfl(part[j & 3], (j >> 2) << 4);
  float mx = -1e30f;
  #pragma unroll
  for (int j = 0; j < 16; ++j) mx = fmaxf(mx, lg[j >> 2][j & 3]);
  float sum = 0.f;
  #pragma unroll
  for (int j = 0; j < 16; ++j) {
    const float e = __expf(lg[j >> 2][j & 3] - mx);
    lg[j >> 2][j & 3] = e; sum += e;
  }
  const float rs = 1.f / sum;
  float den = 1e-8f;
  #pragma unroll
  for (int q4 = 0; q4 < 4; ++q4) {
    f32x4 wvq = *(const f32x4*)(nwts + gr * KNBR + q4 * 4);
    #pragma unroll
    for (int e = 0; e < 4; ++e) { const float a = lg[q4][e] * rs * wvq[e]; lg[q4][e] = a; den += a; }
  }
  const float rd = 1.f / den;

  // context: lane owns dims lane*4..+3 (verified)
  f32x4 cx;
  cx[0]=0.f; cx[1]=0.f; cx[2]=0.f; cx[3]=0.f;
  #pragma unroll
  for (int j = 0; j < 16; ++j) {
    short4v nv = *(const short4v*)&sNbr[w * 4096 + ((j * 256 + lane * 4) ^ ((j & 7) << 3))];
    const float aj = lg[j >> 2][j & 3];
    cx[0] += aj * bf2f(nv[0]); cx[1] += aj * bf2f(nv[1]);
    cx[2] += aj * bf2f(nv[2]); cx[3] += aj * bf2f(nv[3]);
  }
  short4v co;
  co[0] = f2bf(cx[0] * rd); co[1] = f2bf(cx[1] * rd);
  co[2] = f2bf(cx[2] * rd); co[3] = f2bf(cx[3] * rd);
  *(short4v*)(ctxg + gr * DDIM + lane * 4) = co;   // coalesced bf16 ctx to ws
}

// ==================== Kernel B: gate GEMM + epilogue, 16 rows/block (verbatim r3) ====================
__global__ __launch_bounds__(NTHREADS, 4)
void natt_gate(const float* __restrict__ center, const short* __restrict__ ctxg,
               const void* __restrict__ vmask, const short* __restrict__ WF,
               const float* __restrict__ bg, float* __restrict__ out) {
  __shared__ __align__(16) short sCen[4096];
  __shared__ __align__(16) short sCtx[4096];
  const int tid  = threadIdx.x;
  const int lane = tid & 63;
  const int w    = tid >> 6;
  const int n16  = lane & 15;
  const int g4   = lane >> 4;
  const int row0 = blockIdx.x * 16;
  const unsigned char* mb = (const unsigned char*)vmask;
  const short* WgF = WF + 32768;

  // valid_mask dtype detection (verified)
  const unsigned char x1 = mb[lane * 4 + 1];
  const unsigned char x2 = mb[lane * 4 + 2];
  const unsigned char x3 = mb[lane * 4 + 3];
  const bool anyGe2 = __ballot((x1 >= 2) || (x2 >= 2) || (x3 >= 2)) != 0ULL;
  const bool anyNz  = __ballot(((x1 | x2) | x3) != 0) != 0ULL;
  const bool maskIsByte = anyNz && !anyGe2;

  // stage center (verified) + ctx (same pattern, 8B bf16 loads)
  #pragma unroll
  for (int it = 0; it < 4; ++it) {
    const int row = it * 4 + w;
    const int d   = lane * 4;
    float4 v = *(const float4*)(center + (size_t)(row0 + row) * DDIM + d);
    short4v o;
    o[0] = f2bf(v.x); o[1] = f2bf(v.y); o[2] = f2bf(v.z); o[3] = f2bf(v.w);
    *(short4v*)&sCen[(row * 256 + d) ^ ((row & 7) << 3)] = o;
    short4v cv = *(const short4v*)(ctxg + (size_t)(row0 + row) * DDIM + d);
    *(short4v*)&sCtx[(row * 256 + d) ^ ((row & 7) << 3)] = cv;
  }
  __syncthreads();

  // gate GEMM (verbatim r3): M=16 rows, N=256, K=512
  f32x4 gacc[4];
  #pragma unroll
  for (int t = 0; t < 4; ++t) { gacc[t][0]=0.f; gacc[t][1]=0.f; gacc[t][2]=0.f; gacc[t][3]=0.f; }
  #pragma unroll
  for (int s = 0; s < 16; ++s) {
    bf16x8 af;
    if (s < 8) {
      af = *(const bf16x8*)&sCen[(n16 * 256 + s * 32 + g4 * 8) ^ ((n16 & 7) << 3)];
    } else {
      af = *(const bf16x8*)&sCtx[(n16 * 256 + (s - 8) * 32 + g4 * 8) ^ ((n16 & 7) << 3)];
    }
    #pragma unroll
    for (int tt = 0; tt < 4; ++tt) {
      bf16x8 bfr = *(const bf16x8*)&WgF[((w * 4 + tt) * 16 + s) * 512 + lane * 8];
      gacc[tt] = __builtin_amdgcn_mfma_f32_16x16x32_bf16(af, bfr, gacc[tt], 0, 0, 0);
    }
  }
  #pragma unroll
  for (int tt = 0; tt < 4; ++tt) {
    const int dout = (w * 4 + tt) * 16 + n16;
    const float bga = bg[dout];
    #pragma unroll
    for (int r = 0; r < 4; ++r) {
      const int rowl = g4 * 4 + r;
      const size_t gr = (size_t)(row0 + rowl);
      const float pre  = gacc[tt][r] + bga;
      const float gate = 1.f / (1.f + __expf(-pre));
      const float cen  = center[gr * DDIM + dout];
      const float cxv  = bf2f(sCtx[(rowl * 256 + dout) ^ ((rowl & 7) << 3)]);
      const float fused = gate * cen + (1.f - gate) * cxv;
      const bool valid = maskIsByte ? (mb[gr] != 0)
                                    : (((const unsigned int*)vmask)[gr] != 0u);
      out[gr * DDIM + dout] = valid ? fused : cen;
    }
  }
}

// ================= fallback (ws too small): r2-equivalent fused kernel =================
__global__ __launch_bounds__(NTHREADS, 3)
void natt_fb(const float* __restrict__ center, const float* __restrict__ neigh,
             const float* __restrict__ nwts, const void* __restrict__ vmask,
             const float* __restrict__ Wq, const float* __restrict__ bq,
             const float* __restrict__ Wk, const float* __restrict__ bk,
             const float* __restrict__ Wg, const float* __restrict__ bg,
             float* __restrict__ out) {
  __shared__ __align__(16) short smem[24576];
  const int tid  = threadIdx.x;
  const int lane = tid & 63;
  const int w    = tid >> 6;
  const int n16  = lane & 15;
  const int g4   = lane >> 4;
  const int row0 = blockIdx.x * 16;
  const unsigned char* mb = (const unsigned char*)vmask;

  const unsigned char x1 = mb[lane * 4 + 1];
  const unsigned char x2 = mb[lane * 4 + 2];
  const unsigned char x3 = mb[lane * 4 + 3];
  const bool anyGe2 = __ballot((x1 >= 2) || (x2 >= 2) || (x3 >= 2)) != 0ULL;
  const bool anyNz  = __ballot(((x1 | x2) | x3) != 0) != 0ULL;
  const bool maskIsByte = anyNz && !anyGe2;

  #pragma unroll
  for (int it = 0; it < 4; ++it) {
    const int row = it * 4 + w;
    const int d   = lane * 4;
    float4 v = *(const float4*)(center + (size_t)(row0 + row) * DDIM + d);
    short4v o;
    o[0] = f2bf(v.x); o[1] = f2bf(v.y); o[2] = f2bf(v.z); o[3] = f2bf(v.w);
    *(short4v*)&smem[16384 + ((row * 512 + d) ^ ((row & 7) << 3))] = o;
  }
  __syncthreads();

  f32x4 qacc[4];
  #pragma unroll
  for (int t = 0; t < 4; ++t) { qacc[t][0]=0.f; qacc[t][1]=0.f; qacc[t][2]=0.f; qacc[t][3]=0.f; }
  #pragma unroll
  for (int s = 0; s < 8; ++s) {
    bf16x8 af = *(const bf16x8*)&smem[16384 + ((n16 * 512 + s * 32 + g4 * 8) ^ ((n16 & 7) << 3))];
    #pragma unroll
    for (int t = 0; t < 4; ++t) {
      bf16x8 bfr = ldWfrag(Wq, DDIM, t * 16 + n16, s * 32 + g4 * 8);
      qacc[t] = __builtin_amdgcn_mfma_f32_16x16x32_bf16(af, bfr, qacc[t], 0, 0, 0);
    }
  }
  f32x4 bqv, bkv;
  #pragma unroll
  for (int t = 0; t < 4; ++t) { bqv[t] = bq[t * 16 + n16]; bkv[t] = bk[t * 16 + n16]; }

  for (int rr = 0; rr < 4; ++rr) {
    const int rowl = w * 4 + rr;
    const size_t gr = (size_t)(row0 + rowl);
    const float4* np = (const float4*)(neigh + gr * (size_t)(KNBR * DDIM));
    {
      float4 vb[8];
      #pragma unroll
      for (int j = 0; j < 8; ++j) vb[j] = np[j * 64 + lane];
      #pragma unroll
      for (int j = 0; j < 8; ++j) {
        short4v o;
        o[0]=f2bf(vb[j].x); o[1]=f2bf(vb[j].y); o[2]=f2bf(vb[j].z); o[3]=f2bf(vb[j].w);
        *(short4v*)&smem[w * 4096 + ((j * 256 + lane * 4) ^ ((j & 7) << 3))] = o;
      }
      #pragma unroll
      for (int j = 0; j < 8; ++j) vb[j] = np[(j + 8) * 64 + lane];
      #pragma unroll
      for (int j = 0; j < 8; ++j) {
        short4v o;
        o[0]=f2bf(vb[j].x); o[1]=f2bf(vb[j].y); o[2]=f2bf(vb[j].z); o[3]=f2bf(vb[j].w);
        *(short4v*)&smem[w * 4096 + (((j + 8) * 256 + lane * 4) ^ (((j + 8) & 7) << 3))] = o;
      }
    }
    f32x4 kacc[4];
    #pragma unroll
    for (int t = 0; t < 4; ++t) { kacc[t][0]=0.f; kacc[t][1]=0.f; kacc[t][2]=0.f; kacc[t][3]=0.f; }
    #pragma unroll
    for (int s = 0; s < 8; ++s) {
      bf16x8 af = *(const bf16x8*)&smem[w * 4096 +
                    ((n16 * 256 + s * 32 + g4 * 8) ^ ((n16 & 7) << 3))];
      #pragma unroll
      for (int t = 0; t < 4; ++t) {
        bf16x8 bfr = ldWfrag(Wk, DDIM, t * 16 + n16, s * 32 + g4 * 8);
        kacc[t] = __builtin_amdgcn_mfma_f32_16x16x32_bf16(af, bfr, kacc[t], 0, 0, 0);
      }
    }
    f32x4 part;
    part[0]=0.f; part[1]=0.f; part[2]=0.f; part[3]=0.f;
    #pragma unroll
    for (int t = 0; t < 4; ++t) {
      float qv = qacc[t][0];
      if (rr == 1) qv = qacc[t][1];
      if (rr == 2) qv = qacc[t][2];
      if (rr == 3) qv = qacc[t][3];
      qv = __shfl(qv + bqv[t], w * 16 + n16);
      #pragma unroll
      for (int r = 0; r < 4; ++r) part[r] += qv * (kacc[t][r] + bkv[t]);
    }
    #pragma unroll
    for (int off = 1; off < 16; off <<= 1) {
      #pragma unroll
      for (int r = 0; r < 4; ++r) part[r] += __shfl_xor(part[r], off);
    }
    f32x4 lg[4];
    #pragma unroll
    for (int j = 0; j < 16; ++j)
      lg[j >> 2][j & 3] = 0.125f * __shfl(part[j & 3], (j >> 2) << 4);
    float mx = -1e30f;
    #pragma unroll
    for (int j = 0; j < 16; ++j) mx = fmaxf(mx, lg[j >> 2][j & 3]);
    float sum = 0.f;
    #pragma unroll
    for (int j = 0; j < 16; ++j) {
      const float e = __expf(lg[j >> 2][j & 3] - mx);
      lg[j >> 2][j & 3] = e; sum += e;
    }
    const float rs = 1.f / sum;
    float den = 1e-8f;
    #pragma unroll
    for (int q4 = 0; q4 < 4; ++q4) {
      f32x4 wvq = *(const f32x4*)(nwts + gr * KNBR + q4 * 4);
      #pragma unroll
      for (int e = 0; e < 4; ++e) { const float a = lg[q4][e] * rs * wvq[e]; lg[q4][e] = a; den += a; }
    }
    const float rd = 1.f / den;
    f32x4 cx;
    cx[0]=0.f; cx[1]=0.f; cx[2]=0.f; cx[3]=0.f;
    #pragma unroll
    for (int j = 0; j < 16; ++j) {
      short4v nv = *(const short4v*)&smem[w * 4096 + ((j * 256 + lane * 4) ^ ((j & 7) << 3))];
      const float aj = lg[j >> 2][j & 3];
      cx[0] += aj * bf2f(nv[0]); cx[1] += aj * bf2f(nv[1]);
      cx[2] += aj * bf2f(nv[2]); cx[3] += aj * bf2f(nv[3]);
    }
    short4v co;
    co[0] = f2bf(cx[0] * rd); co[1] = f2bf(cx[1] * rd);
    co[2] = f2bf(cx[2] * rd); co[3] = f2bf(cx[3] * rd);
    *(short4v*)&smem[16384 + ((rowl * 512 + 256 + lane * 4) ^ ((rowl & 7) << 3))] = co;
  }
  __syncthreads();

  f32x4 gacc[4];
  #pragma unroll
  for (int t = 0; t < 4; ++t) { gacc[t][0]=0.f; gacc[t][1]=0.f; gacc[t][2]=0.f; gacc[t][3]=0.f; }
  #pragma unroll
  for (int s = 0; s < 16; ++s) {
    bf16x8 af = *(const bf16x8*)&smem[16384 + ((n16 * 512 + s * 32 + g4 * 8) ^ ((n16 & 7) << 3))];
    #pragma unroll
    for (int tt = 0; tt < 4; ++tt) {
      bf16x8 bfr = ldWfrag(Wg, TWOD, (w * 4 + tt) * 16 + n16, s * 32 + g4 * 8);
      gacc[tt] = __builtin_amdgcn_mfma_f32_16x16x32_bf16(af, bfr, gacc[tt], 0, 0, 0);
    }
  }
  #pragma unroll
  for (int tt = 0; tt < 4; ++tt) {
    const int dout = (w * 4 + tt) * 16 + n16;
    const float bga = bg[dout];
    #pragma unroll
    for (int r = 0; r < 4; ++r) {
      const int rowl = g4 * 4 + r;
      const size_t gr = (size_t)(row0 + rowl);
      const float pre  = gacc[tt][r] + bga;
      const float gate = 1.f / (1.f + __expf(-pre));
      const float cen  = center[gr * DDIM + dout];
      const float cxv  = bf2f(smem[16384 + ((rowl * 512 + 256 + dout) ^ ((rowl & 7) << 3))]);
      const float fused = gate * cen + (1.f - gate) * cxv;
      const bool valid = maskIsByte ? (mb[gr] != 0)
                                    : (((const unsigned int*)vmask)[gr] != 0u);
      out[gr * DDIM + dout] = valid ? fused : cen;
    }
  }
}

extern "C" void kernel_launch(void* const* d_in, const int* in_sizes, int n_in,
                              void* d_out, int out_size, void* d_ws, size_t ws_size,
                              hipStream_t stream) {
  const float* center = (const float*)d_in[0];
  const float* neigh  = (const float*)d_in[1];
  const float* nwts   = (const float*)d_in[2];
  const void*  vm     = d_in[3];
  const float* Wq = (const float*)d_in[4];
  const float* bq = (const float*)d_in[5];
  const float* Wk = (const float*)d_in[6];
  const float* bk = (const float*)d_in[7];
  const float* Wg = (const float*)d_in[8];
  const float* bg = (const float*)d_in[9];
  float* out = (float*)d_out;

  const int nrows = in_sizes[0] / DDIM;           // 32768
  dim3 block(NTHREADS);

  if (ws_size >= (size_t)WS_NEED) {
    short* WF   = (short*)d_ws;
    short* ctxg = WF + CTX_SOFF;
    hipLaunchKernelGGL(prep_frags, dim3(80), block, 0, stream, Wq, Wk, Wg, WF);
    hipLaunchKernelGGL(natt_ctx, dim3(nrows / 4), block, 0, stream,
                       center, neigh, nwts, WF, bq, bk, ctxg);
    hipLaunchKernelGGL(natt_gate, dim3(nrows / 16), block, 0, stream,
                       center, ctxg, vm, WF, bg, out);
  } else {
    hipLaunchKernelGGL(natt_fb, dim3(nrows / 16), block, 0, stream,
                       center, neigh, nwts, vm, Wq, bq, Wk, bk, Wg, bg, out);
  }
}

// Round 9
// 177.704 us; speedup vs baseline: 2.3443x; 1.4836x over previous
//
#include <hip/hip_runtime.h>
#include <hip/hip_bf16.h>

#define DDIM   256
#define KNBR   16
#define TWOD   512
#define NTHREADS 256

using bf16x8  = __attribute__((ext_vector_type(8))) short;
using short4v = __attribute__((ext_vector_type(4))) short;
using f32x4   = __attribute__((ext_vector_type(4))) float;

// ---- ws layout: WF shorts [0,163840) | ctxg bf16 [32768][256] | qg f32 [32768][64]
#define CTX_SOFF 163840u
#define QG_BOFF  17104896u               // bytes: 327680 + 16777216
#define WS_NEED  25493504u               // + 8388608 (qg)

__device__ __forceinline__ short f2bf(float x) {
  unsigned int u;
  __builtin_memcpy(&u, &x, 4);
  u += 0x7FFFu + ((u >> 16) & 1u);   // RNE
  return (short)(u >> 16);
}
__device__ __forceinline__ float bf2f(short s) {
  unsigned int u = ((unsigned int)(unsigned short)s) << 16;
  float f;
  __builtin_memcpy(&f, &u, 4);
  return f;
}

// Verified B-fragment loader (fallback path only)
__device__ __forceinline__ bf16x8 ldWfrag(const float* __restrict__ W, int ld, int r, int c) {
  const float4* p = (const float4*)(W + (size_t)r * ld + c);
  float4 a = p[0];
  float4 b = p[1];
  bf16x8 o;
  o[0] = f2bf(a.x); o[1] = f2bf(a.y); o[2] = f2bf(a.z); o[3] = f2bf(a.w);
  o[4] = f2bf(b.x); o[5] = f2bf(b.y); o[6] = f2bf(b.z); o[7] = f2bf(b.w);
  return o;
}

// ---- prep_frags: VERBATIM (HW-passed). WqF(32) WkF(32) WgF(256) ----
__global__ void prep_frags(const float* __restrict__ Wq,
                           const float* __restrict__ Wk,
                           const float* __restrict__ Wg,
                           short* __restrict__ F) {
  const int gid  = blockIdx.x * NTHREADS + threadIdx.x;
  const int lane = gid & 63;
  const int n16  = lane & 15;
  const int g4   = lane >> 4;
  const int f    = gid >> 6;                 // 0..319
  const float* src;
  short* dst;
  if (f < 32) {
    const int t = f >> 3, s = f & 7;
    src = Wq + (size_t)(t * 16 + n16) * DDIM + s * 32 + g4 * 8;
    dst = F + f * 512 + lane * 8;
  } else if (f < 64) {
    const int fq = f - 32;
    const int t = fq >> 3, s = fq & 7;
    src = Wk + (size_t)(t * 16 + n16) * DDIM + s * 32 + g4 * 8;
    dst = F + 16384 + fq * 512 + lane * 8;
  } else {
    const int fg = f - 64;                   // 0..255
    const int t4 = fg >> 4, s = fg & 15;
    src = Wg + (size_t)(t4 * 16 + n16) * TWOD + s * 32 + g4 * 8;
    dst = F + 32768 + fg * 512 + lane * 8;
  }
  float4 a = *(const float4*)src;
  float4 b = *(const float4*)(src + 4);
  bf16x8 o;
  o[0] = f2bf(a.x); o[1] = f2bf(a.y); o[2] = f2bf(a.z); o[3] = f2bf(a.w);
  o[4] = f2bf(b.x); o[5] = f2bf(b.y); o[6] = f2bf(b.z); o[7] = f2bf(b.w);
  *(bf16x8*)dst = o;
}

// ==================== k_q: q = center*Wq^T + bq (f32 to ws), 16 rows/block ====================
__global__ __launch_bounds__(NTHREADS, 4)
void k_q(const float* __restrict__ center, const short* __restrict__ WF,
         const float* __restrict__ bq, float* __restrict__ qg) {
  __shared__ __align__(16) short sCen[4096];
  const int tid  = threadIdx.x;
  const int lane = tid & 63;
  const int w    = tid >> 6;
  const int n16  = lane & 15;
  const int g4   = lane >> 4;
  const int row0 = blockIdx.x * 16;
  const short* WqF = WF;

  // stage 16 center rows (verified pattern)
  #pragma unroll
  for (int it = 0; it < 4; ++it) {
    const int row = it * 4 + w;
    const int d   = lane * 4;
    float4 v = *(const float4*)(center + (size_t)(row0 + row) * DDIM + d);
    short4v o;
    o[0] = f2bf(v.x); o[1] = f2bf(v.y); o[2] = f2bf(v.z); o[3] = f2bf(v.w);
    *(short4v*)&sCen[(row * 256 + d) ^ ((row & 7) << 3)] = o;
  }
  __syncthreads();

  // wave w computes column tile t=w (a = w*16+n16), verified mechanics
  f32x4 qacc;
  qacc[0]=0.f; qacc[1]=0.f; qacc[2]=0.f; qacc[3]=0.f;
  #pragma unroll
  for (int s = 0; s < 8; ++s) {
    bf16x8 af = *(const bf16x8*)&sCen[(n16 * 256 + s * 32 + g4 * 8) ^ ((n16 & 7) << 3)];
    bf16x8 bfr = *(const bf16x8*)&WqF[(w * 8 + s) * 512 + lane * 8];
    qacc = __builtin_amdgcn_mfma_f32_16x16x32_bf16(af, bfr, qacc, 0, 0, 0);
  }
  const float bqa = bq[w * 16 + n16];
  #pragma unroll
  for (int r = 0; r < 4; ++r) {
    const size_t row = (size_t)(row0 + g4 * 4 + r);
    qg[row * 64 + w * 16 + n16] = qacc[r] + bqa;   // C/D map: col=n16, row=g4*4+r (verified)
  }
}

// ==================== Kernel A v2: loads-first streaming, 1 row/wave, no barrier ====================
// LDS: sNbr 32KB (4 waves x [16][256] bf16 swz)
__global__ __launch_bounds__(NTHREADS, 4)
void natt_ctx2(const float* __restrict__ neigh, const float* __restrict__ nwts,
               const float* __restrict__ qg, const short* __restrict__ WF,
               const float* __restrict__ bk, short* __restrict__ ctxg) {
  __shared__ __align__(16) short sNbr[16384];
  const int tid  = threadIdx.x;
  const int lane = tid & 63;
  const int w    = tid >> 6;
  const int n16  = lane & 15;
  const int g4   = lane >> 4;
  const size_t gr = (size_t)blockIdx.x * 4 + w;
  const short* WkF = WF + 16384;

  // ---- issue the 16 KB/wave neighbor burst FIRST ----
  const float4* np = (const float4*)(neigh + gr * (size_t)(KNBR * DDIM));
  float4 nb0 = np[0*64+lane], nb1 = np[1*64+lane], nb2 = np[2*64+lane], nb3 = np[3*64+lane];
  float4 nb4 = np[4*64+lane], nb5 = np[5*64+lane], nb6 = np[6*64+lane], nb7 = np[7*64+lane];
  float4 nb8 = np[8*64+lane], nb9 = np[9*64+lane], nbA = np[10*64+lane], nbB = np[11*64+lane];
  float4 nbC = np[12*64+lane], nbD = np[13*64+lane], nbE = np[14*64+lane], nbF = np[15*64+lane];
  f32x4 w0 = *(const f32x4*)(nwts + gr * KNBR + 0);
  f32x4 w1 = *(const f32x4*)(nwts + gr * KNBR + 4);
  f32x4 w2 = *(const f32x4*)(nwts + gr * KNBR + 8);
  f32x4 w3 = *(const f32x4*)(nwts + gr * KNBR + 12);
  f32x4 qvv, bkv;
  #pragma unroll
  for (int t = 0; t < 4; ++t) {
    qvv[t] = qg[gr * 64 + t * 16 + n16];
    bkv[t] = bk[t * 16 + n16];
  }

  // ---- stage to LDS bf16 swz (named regs, static indices) ----
  #define STG(j, v) { short4v o_;                                                   \
    o_[0]=f2bf((v).x); o_[1]=f2bf((v).y); o_[2]=f2bf((v).z); o_[3]=f2bf((v).w);     \
    *(short4v*)&sNbr[w * 4096 + (((j) * 256 + lane * 4) ^ (((j) & 7) << 3))] = o_; }
  STG(0,nb0)  STG(1,nb1)  STG(2,nb2)  STG(3,nb3)
  STG(4,nb4)  STG(5,nb5)  STG(6,nb6)  STG(7,nb7)
  STG(8,nb8)  STG(9,nb9)  STG(10,nbA) STG(11,nbB)
  STG(12,nbC) STG(13,nbD) STG(14,nbE) STG(15,nbF)
  #undef STG

  // ---- k-projection: M=16 neighbors, N=64, K=256 (verified) ----
  f32x4 kacc[4];
  #pragma unroll
  for (int t = 0; t < 4; ++t) { kacc[t][0]=0.f; kacc[t][1]=0.f; kacc[t][2]=0.f; kacc[t][3]=0.f; }
  #pragma unroll
  for (int s = 0; s < 8; ++s) {
    bf16x8 af = *(const bf16x8*)&sNbr[w * 4096 +
                  ((n16 * 256 + s * 32 + g4 * 8) ^ ((n16 & 7) << 3))];
    #pragma unroll
    for (int t = 0; t < 4; ++t) {
      bf16x8 bfr = *(const bf16x8*)&WkF[(t * 8 + s) * 512 + lane * 8];
      kacc[t] = __builtin_amdgcn_mfma_f32_16x16x32_bf16(af, bfr, kacc[t], 0, 0, 0);
    }
  }

  // ---- logits (verified r8 path; q from qg) ----
  f32x4 part;
  part[0]=0.f; part[1]=0.f; part[2]=0.f; part[3]=0.f;
  #pragma unroll
  for (int t = 0; t < 4; ++t) {
    #pragma unroll
    for (int r = 0; r < 4; ++r) part[r] += qvv[t] * (kacc[t][r] + bkv[t]);
  }
  #pragma unroll
  for (int off = 1; off < 16; off <<= 1) {
    #pragma unroll
    for (int r = 0; r < 4; ++r) part[r] += __shfl_xor(part[r], off);
  }
  f32x4 lg[4];
  #pragma unroll
  for (int j = 0; j < 16; ++j)
    lg[j >> 2][j & 3] = 0.125f * __shfl(part[j & 3], (j >> 2) << 4);
  float mx = -1e30f;
  #pragma unroll
  for (int j = 0; j < 16; ++j) mx = fmaxf(mx, lg[j >> 2][j & 3]);
  float sum = 0.f;
  #pragma unroll
  for (int j = 0; j < 16; ++j) {
    const float e = __expf(lg[j >> 2][j & 3] - mx);
    lg[j >> 2][j & 3] = e; sum += e;
  }
  const float rs = 1.f / sum;
  float den = 1e-8f;
  #pragma unroll
  for (int e = 0; e < 4; ++e) {
    lg[0][e] *= rs * w0[e]; den += lg[0][e];
    lg[1][e] *= rs * w1[e]; den += lg[1][e];
    lg[2][e] *= rs * w2[e]; den += lg[2][e];
    lg[3][e] *= rs * w3[e]; den += lg[3][e];
  }
  const float rd = 1.f / den;

  // ---- context from LDS (verified) ----
  f32x4 cx;
  cx[0]=0.f; cx[1]=0.f; cx[2]=0.f; cx[3]=0.f;
  #pragma unroll
  for (int j = 0; j < 16; ++j) {
    short4v nv = *(const short4v*)&sNbr[w * 4096 + ((j * 256 + lane * 4) ^ ((j & 7) << 3))];
    const float aj = lg[j >> 2][j & 3];
    cx[0] += aj * bf2f(nv[0]); cx[1] += aj * bf2f(nv[1]);
    cx[2] += aj * bf2f(nv[2]); cx[3] += aj * bf2f(nv[3]);
  }
  short4v co;
  co[0] = f2bf(cx[0] * rd); co[1] = f2bf(cx[1] * rd);
  co[2] = f2bf(cx[2] * rd); co[3] = f2bf(cx[3] * rd);
  *(short4v*)(ctxg + gr * DDIM + lane * 4) = co;
}

// ==================== Kernel B: gate GEMM + epilogue (VERBATIM r8, HW-passed) ====================
__global__ __launch_bounds__(NTHREADS, 4)
void natt_gate(const float* __restrict__ center, const short* __restrict__ ctxg,
               const void* __restrict__ vmask, const short* __restrict__ WF,
               const float* __restrict__ bg, float* __restrict__ out) {
  __shared__ __align__(16) short sCen[4096];
  __shared__ __align__(16) short sCtx[4096];
  const int tid  = threadIdx.x;
  const int lane = tid & 63;
  const int w    = tid >> 6;
  const int n16  = lane & 15;
  const int g4   = lane >> 4;
  const int row0 = blockIdx.x * 16;
  const unsigned char* mb = (const unsigned char*)vmask;
  const short* WgF = WF + 32768;

  const unsigned char x1 = mb[lane * 4 + 1];
  const unsigned char x2 = mb[lane * 4 + 2];
  const unsigned char x3 = mb[lane * 4 + 3];
  const bool anyGe2 = __ballot((x1 >= 2) || (x2 >= 2) || (x3 >= 2)) != 0ULL;
  const bool anyNz  = __ballot(((x1 | x2) | x3) != 0) != 0ULL;
  const bool maskIsByte = anyNz && !anyGe2;

  #pragma unroll
  for (int it = 0; it < 4; ++it) {
    const int row = it * 4 + w;
    const int d   = lane * 4;
    float4 v = *(const float4*)(center + (size_t)(row0 + row) * DDIM + d);
    short4v o;
    o[0] = f2bf(v.x); o[1] = f2bf(v.y); o[2] = f2bf(v.z); o[3] = f2bf(v.w);
    *(short4v*)&sCen[(row * 256 + d) ^ ((row & 7) << 3)] = o;
    short4v cv = *(const short4v*)(ctxg + (size_t)(row0 + row) * DDIM + d);
    *(short4v*)&sCtx[(row * 256 + d) ^ ((row & 7) << 3)] = cv;
  }
  __syncthreads();

  f32x4 gacc[4];
  #pragma unroll
  for (int t = 0; t < 4; ++t) { gacc[t][0]=0.f; gacc[t][1]=0.f; gacc[t][2]=0.f; gacc[t][3]=0.f; }
  #pragma unroll
  for (int s = 0; s < 16; ++s) {
    bf16x8 af;
    if (s < 8) {
      af = *(const bf16x8*)&sCen[(n16 * 256 + s * 32 + g4 * 8) ^ ((n16 & 7) << 3)];
    } else {
      af = *(const bf16x8*)&sCtx[(n16 * 256 + (s - 8) * 32 + g4 * 8) ^ ((n16 & 7) << 3)];
    }
    #pragma unroll
    for (int tt = 0; tt < 4; ++tt) {
      bf16x8 bfr = *(const bf16x8*)&WgF[((w * 4 + tt) * 16 + s) * 512 + lane * 8];
      gacc[tt] = __builtin_amdgcn_mfma_f32_16x16x32_bf16(af, bfr, gacc[tt], 0, 0, 0);
    }
  }
  #pragma unroll
  for (int tt = 0; tt < 4; ++tt) {
    const int dout = (w * 4 + tt) * 16 + n16;
    const float bga = bg[dout];
    #pragma unroll
    for (int r = 0; r < 4; ++r) {
      const int rowl = g4 * 4 + r;
      const size_t gr = (size_t)(row0 + rowl);
      const float pre  = gacc[tt][r] + bga;
      const float gate = 1.f / (1.f + __expf(-pre));
      const float cen  = center[gr * DDIM + dout];
      const float cxv  = bf2f(sCtx[(rowl * 256 + dout) ^ ((rowl & 7) << 3)]);
      const float fused = gate * cen + (1.f - gate) * cxv;
      const bool valid = maskIsByte ? (mb[gr] != 0)
                                    : (((const unsigned int*)vmask)[gr] != 0u);
      out[gr * DDIM + dout] = valid ? fused : cen;
    }
  }
}

// ================= fallback (ws too small): VERBATIM r8 fused kernel =================
__global__ __launch_bounds__(NTHREADS, 3)
void natt_fb(const float* __restrict__ center, const float* __restrict__ neigh,
             const float* __restrict__ nwts, const void* __restrict__ vmask,
             const float* __restrict__ Wq, const float* __restrict__ bq,
             const float* __restrict__ Wk, const float* __restrict__ bk,
             const float* __restrict__ Wg, const float* __restrict__ bg,
             float* __restrict__ out) {
  __shared__ __align__(16) short smem[24576];
  const int tid  = threadIdx.x;
  const int lane = tid & 63;
  const int w    = tid >> 6;
  const int n16  = lane & 15;
  const int g4   = lane >> 4;
  const int row0 = blockIdx.x * 16;
  const unsigned char* mb = (const unsigned char*)vmask;

  const unsigned char x1 = mb[lane * 4 + 1];
  const unsigned char x2 = mb[lane * 4 + 2];
  const unsigned char x3 = mb[lane * 4 + 3];
  const bool anyGe2 = __ballot((x1 >= 2) || (x2 >= 2) || (x3 >= 2)) != 0ULL;
  const bool anyNz  = __ballot(((x1 | x2) | x3) != 0) != 0ULL;
  const bool maskIsByte = anyNz && !anyGe2;

  #pragma unroll
  for (int it = 0; it < 4; ++it) {
    const int row = it * 4 + w;
    const int d   = lane * 4;
    float4 v = *(const float4*)(center + (size_t)(row0 + row) * DDIM + d);
    short4v o;
    o[0] = f2bf(v.x); o[1] = f2bf(v.y); o[2] = f2bf(v.z); o[3] = f2bf(v.w);
    *(short4v*)&smem[16384 + ((row * 512 + d) ^ ((row & 7) << 3))] = o;
  }
  __syncthreads();

  f32x4 qacc[4];
  #pragma unroll
  for (int t = 0; t < 4; ++t) { qacc[t][0]=0.f; qacc[t][1]=0.f; qacc[t][2]=0.f; qacc[t][3]=0.f; }
  #pragma unroll
  for (int s = 0; s < 8; ++s) {
    bf16x8 af = *(const bf16x8*)&smem[16384 + ((n16 * 512 + s * 32 + g4 * 8) ^ ((n16 & 7) << 3))];
    #pragma unroll
    for (int t = 0; t < 4; ++t) {
      bf16x8 bfr = ldWfrag(Wq, DDIM, t * 16 + n16, s * 32 + g4 * 8);
      qacc[t] = __builtin_amdgcn_mfma_f32_16x16x32_bf16(af, bfr, qacc[t], 0, 0, 0);
    }
  }
  f32x4 bqv, bkv;
  #pragma unroll
  for (int t = 0; t < 4; ++t) { bqv[t] = bq[t * 16 + n16]; bkv[t] = bk[t * 16 + n16]; }

  for (int rr = 0; rr < 4; ++rr) {
    const int rowl = w * 4 + rr;
    const size_t gr = (size_t)(row0 + rowl);
    const float4* np = (const float4*)(neigh + gr * (size_t)(KNBR * DDIM));
    {
      float4 vb[8];
      #pragma unroll
      for (int j = 0; j < 8; ++j) vb[j] = np[j * 64 + lane];
      #pragma unroll
      for (int j = 0; j < 8; ++j) {
        short4v o;
        o[0]=f2bf(vb[j].x); o[1]=f2bf(vb[j].y); o[2]=f2bf(vb[j].z); o[3]=f2bf(vb[j].w);
        *(short4v*)&smem[w * 4096 + ((j * 256 + lane * 4) ^ ((j & 7) << 3))] = o;
      }
      #pragma unroll
      for (int j = 0; j < 8; ++j) vb[j] = np[(j + 8) * 64 + lane];
      #pragma unroll
      for (int j = 0; j < 8; ++j) {
        short4v o;
        o[0]=f2bf(vb[j].x); o[1]=f2bf(vb[j].y); o[2]=f2bf(vb[j].z); o[3]=f2bf(vb[j].w);
        *(short4v*)&smem[w * 4096 + (((j + 8) * 256 + lane * 4) ^ (((j + 8) & 7) << 3))] = o;
      }
    }
    f32x4 kacc[4];
    #pragma unroll
    for (int t = 0; t < 4; ++t) { kacc[t][0]=0.f; kacc[t][1]=0.f; kacc[t][2]=0.f; kacc[t][3]=0.f; }
    #pragma unroll
    for (int s = 0; s < 8; ++s) {
      bf16x8 af = *(const bf16x8*)&smem[w * 4096 +
                    ((n16 * 256 + s * 32 + g4 * 8) ^ ((n16 & 7) << 3))];
      #pragma unroll
      for (int t = 0; t < 4; ++t) {
        bf16x8 bfr = ldWfrag(Wk, DDIM, t * 16 + n16, s * 32 + g4 * 8);
        kacc[t] = __builtin_amdgcn_mfma_f32_16x16x32_bf16(af, bfr, kacc[t], 0, 0, 0);
      }
    }
    f32x4 part;
    part[0]=0.f; part[1]=0.f; part[2]=0.f; part[3]=0.f;
    #pragma unroll
    for (int t = 0; t < 4; ++t) {
      float qv = qacc[t][0];
      if (rr == 1) qv = qacc[t][1];
      if (rr == 2) qv = qacc[t][2];
      if (rr == 3) qv = qacc[t][3];
      qv = __shfl(qv + bqv[t], w * 16 + n16);
      #pragma unroll
      for (int r = 0; r < 4; ++r) part[r] += qv * (kacc[t][r] + bkv[t]);
    }
    #pragma unroll
    for (int off = 1; off < 16; off <<= 1) {
      #pragma unroll
      for (int r = 0; r < 4; ++r) part[r] += __shfl_xor(part[r], off);
    }
    f32x4 lg[4];
    #pragma unroll
    for (int j = 0; j < 16; ++j)
      lg[j >> 2][j & 3] = 0.125f * __shfl(part[j & 3], (j >> 2) << 4);
    float mx = -1e30f;
    #pragma unroll
    for (int j = 0; j < 16; ++j) mx = fmaxf(mx, lg[j >> 2][j & 3]);
    float sum = 0.f;
    #pragma unroll
    for (int j = 0; j < 16; ++j) {
      const float e = __expf(lg[j >> 2][j & 3] - mx);
      lg[j >> 2][j & 3] = e; sum += e;
    }
    const float rs = 1.f / sum;
    float den = 1e-8f;
    #pragma unroll
    for (int q4 = 0; q4 < 4; ++q4) {
      f32x4 wvq = *(const f32x4*)(nwts + gr * KNBR + q4 * 4);
      #pragma unroll
      for (int e = 0; e < 4; ++e) { const float a = lg[q4][e] * rs * wvq[e]; lg[q4][e] = a; den += a; }
    }
    const float rd = 1.f / den;
    f32x4 cx;
    cx[0]=0.f; cx[1]=0.f; cx[2]=0.f; cx[3]=0.f;
    #pragma unroll
    for (int j = 0; j < 16; ++j) {
      short4v nv = *(const short4v*)&smem[w * 4096 + ((j * 256 + lane * 4) ^ ((j & 7) << 3))];
      const float aj = lg[j >> 2][j & 3];
      cx[0] += aj * bf2f(nv[0]); cx[1] += aj * bf2f(nv[1]);
      cx[2] += aj * bf2f(nv[2]); cx[3] += aj * bf2f(nv[3]);
    }
    short4v co;
    co[0] = f2bf(cx[0] * rd); co[1] = f2bf(cx[1] * rd);
    co[2] = f2bf(cx[2] * rd); co[3] = f2bf(cx[3] * rd);
    *(short4v*)&smem[16384 + ((rowl * 512 + 256 + lane * 4) ^ ((rowl & 7) << 3))] = co;
  }
  __syncthreads();

  f32x4 gacc[4];
  #pragma unroll
  for (int t = 0; t < 4; ++t) { gacc[t][0]=0.f; gacc[t][1]=0.f; gacc[t][2]=0.f; gacc[t][3]=0.f; }
  #pragma unroll
  for (int s = 0; s < 16; ++s) {
    bf16x8 af = *(const bf16x8*)&smem[16384 + ((n16 * 512 + s * 32 + g4 * 8) ^ ((n16 & 7) << 3))];
    #pragma unroll
    for (int tt = 0; tt < 4; ++tt) {
      bf16x8 bfr = ldWfrag(Wg, TWOD, (w * 4 + tt) * 16 + n16, s * 32 + g4 * 8);
      gacc[tt] = __builtin_amdgcn_mfma_f32_16x16x32_bf16(af, bfr, gacc[tt], 0, 0, 0);
    }
  }
  #pragma unroll
  for (int tt = 0; tt < 4; ++tt) {
    const int dout = (w * 4 + tt) * 16 + n16;
    const float bga = bg[dout];
    #pragma unroll
    for (int r = 0; r < 4; ++r) {
      const int rowl = g4 * 4 + r;
      const size_t gr = (size_t)(row0 + rowl);
      const float pre  = gacc[tt][r] + bga;
      const float gate = 1.f / (1.f + __expf(-pre));
      const float cen  = center[gr * DDIM + dout];
      const float cxv  = bf2f(smem[16384 + ((rowl * 512 + 256 + dout) ^ ((rowl & 7) << 3))]);
      const float fused = gate * cen + (1.f - gate) * cxv;
      const bool valid = maskIsByte ? (mb[gr] != 0)
                                    : (((const unsigned int*)vmask)[gr] != 0u);
      out[gr * DDIM + dout] = valid ? fused : cen;
    }
  }
}

extern "C" void kernel_launch(void* const* d_in, const int* in_sizes, int n_in,
                              void* d_out, int out_size, void* d_ws, size_t ws_size,
                              hipStream_t stream) {
  const float* center = (const float*)d_in[0];
  const float* neigh  = (const float*)d_in[1];
  const float* nwts   = (const float*)d_in[2];
  const void*  vm     = d_in[3];
  const float* Wq = (const float*)d_in[4];
  const float* bq = (const float*)d_in[5];
  const float* Wk = (const float*)d_in[6];
  const float* bk = (const float*)d_in[7];
  const float* Wg = (const float*)d_in[8];
  const float* bg = (const float*)d_in[9];
  float* out = (float*)d_out;

  const int nrows = in_sizes[0] / DDIM;           // 32768
  dim3 block(NTHREADS);

  if (ws_size >= (size_t)WS_NEED) {
    short* WF   = (short*)d_ws;
    short* ctxg = WF + CTX_SOFF;
    float* qg   = (float*)((char*)d_ws + QG_BOFF);
    hipLaunchKernelGGL(prep_frags, dim3(80), block, 0, stream, Wq, Wk, Wg, WF);
    hipLaunchKernelGGL(k_q, dim3(nrows / 16), block, 0, stream, center, WF, bq, qg);
    hipLaunchKernelGGL(natt_ctx2, dim3(nrows / 4), block, 0, stream,
                       neigh, nwts, qg, WF, bk, ctxg);
    hipLaunchKernelGGL(natt_gate, dim3(nrows / 16), block, 0, stream,
                       center, ctxg, vm, WF, bg, out);
  } else {
    hipLaunchKernelGGL(natt_fb, dim3(nrows / 16), block, 0, stream,
                       center, neigh, nwts, vm, Wq, bq, Wk, bk, Wg, bg, out);
  }
}